// Round 12
// baseline (89.277 us; speedup 1.0000x reference)
//
#include <hip/hip_runtime.h>
#include <hip/hip_bf16.h>

// Problem constants (Head_60421599920770): B=32, T=2048, C=256, HS=64
#define NB 32
#define NT 2048
#define NC 256
#define NH 64
#define QB 64
#define KB 64
#define MT 128   // qkv M-tile rows per block
#define KC 64    // qkv K-chunk

typedef __attribute__((ext_vector_type(8))) short bf16x8;   // 8 bf16 = 4 VGPRs
typedef __attribute__((ext_vector_type(4))) float f32x4;    // MFMA C/D

static constexpr float SCALE2 = 0.18033688011112042f;  // HS^-0.5 * log2(e)
static constexpr float LNEG   = -1e9f;

static __device__ inline short f2b(float x) {
    __hip_bfloat16 h = __float2bfloat16(x);
    return *reinterpret_cast<short*>(&h);
}
static __device__ inline float b2f(short s) {
    unsigned int u = ((unsigned int)(unsigned short)s) << 16;
    float f; __builtin_memcpy(&f, &u, 4); return f;
}

// async global->LDS DMA, 16B per lane; LDS dest = wave-uniform base + lane*16
static __device__ inline void dma16(const __hip_bfloat16* g, __hip_bfloat16* l) {
    __builtin_amdgcn_global_load_lds(
        (const __attribute__((address_space(1))) unsigned int*)g,
        (__attribute__((address_space(3))) unsigned int*)l, 16, 0, 0);
}

// ---------------------------------------------------------------------------
// Merged prep: blocks 0-191 transpose W (Wt[n][k] bf16, n: Q|K|V cols);
// blocks 192-447 build Bias[b][t] = mask ? 0 : -1e9.
// ---------------------------------------------------------------------------
__global__ __launch_bounds__(256) void prep_kernel(
    const float* __restrict__ Wq, const float* __restrict__ Wk,
    const float* __restrict__ Wv, const int* __restrict__ M,
    __hip_bfloat16* __restrict__ Wt, float* __restrict__ Bias)
{
    const int n = blockIdx.x;
    if (n < 192) {
        const int k = threadIdx.x;           // 0..255
        const float* Wm = (n < 64) ? Wq : ((n < 128) ? Wk : Wv);
        Wt[n * NC + k] = __float2bfloat16(Wm[k * NH + (n & 63)]);
    } else {
        const int i = (n - 192) * 256 + threadIdx.x;
        Bias[i] = M[i] ? 0.f : LNEG;
    }
}

// ---------------------------------------------------------------------------
// QKV projection as bf16 MFMA GEMM (verified round 2) + T14 register
// prefetch (verified round 11).
// ---------------------------------------------------------------------------
__global__ __launch_bounds__(256, 2) void qkv_kernel(
    const float* __restrict__ X, const __hip_bfloat16* __restrict__ Wt,
    __hip_bfloat16* __restrict__ Q, __hip_bfloat16* __restrict__ K,
    __hip_bfloat16* __restrict__ Vt)
{
    __shared__ __hip_bfloat16 x_lds[MT][KC + 8];
    __shared__ __hip_bfloat16 w_lds[192][KC + 8];

    const int row0 = blockIdx.x * MT;
    const int tid  = threadIdx.x;
    const int wid  = tid >> 6;
    const int lane = tid & 63;
    const int l15  = lane & 15;
    const int lg   = lane >> 4;

    f32x4 aQ[4][2], aK[4][2], aV[2][4];
    #pragma unroll
    for (int i = 0; i < 4; ++i)
        #pragma unroll
        for (int j = 0; j < 2; ++j) {
            aQ[i][j] = (f32x4){0.f,0.f,0.f,0.f};
            aK[i][j] = (f32x4){0.f,0.f,0.f,0.f};
            aV[j][i] = (f32x4){0.f,0.f,0.f,0.f};
        }

    // ---- prefetch chunk 0 into registers ----
    float4 xp[4][2];
    bf16x8 wp[6];
    #pragma unroll
    for (int i = 0; i < 4; ++i) {
        int u = tid + i * 256;
        int r = u >> 3, c8 = (u & 7) * 8;
        const float* src = &X[(size_t)(row0 + r) * NC + c8];
        xp[i][0] = *(const float4*)(src);
        xp[i][1] = *(const float4*)(src + 4);
    }
    #pragma unroll
    for (int i = 0; i < 6; ++i) {
        int u = tid + i * 256;
        int r = u >> 3, c8 = (u & 7) * 8;
        wp[i] = *reinterpret_cast<const bf16x8*>(&Wt[r * NC + c8]);
    }

    for (int kc = 0; kc < NC / KC; ++kc) {
        __syncthreads();                 // previous chunk fully consumed
        #pragma unroll
        for (int i = 0; i < 4; ++i) {
            int u = tid + i * 256;
            int r = u >> 3, c8 = (u & 7) * 8;
            bf16x8 o;
            o[0]=f2b(xp[i][0].x); o[1]=f2b(xp[i][0].y);
            o[2]=f2b(xp[i][0].z); o[3]=f2b(xp[i][0].w);
            o[4]=f2b(xp[i][1].x); o[5]=f2b(xp[i][1].y);
            o[6]=f2b(xp[i][1].z); o[7]=f2b(xp[i][1].w);
            *reinterpret_cast<bf16x8*>(&x_lds[r][c8]) = o;
        }
        #pragma unroll
        for (int i = 0; i < 6; ++i) {
            int u = tid + i * 256;
            int r = u >> 3, c8 = (u & 7) * 8;
            *reinterpret_cast<bf16x8*>(&w_lds[r][c8]) = wp[i];
        }
        __syncthreads();

        if (kc + 1 < NC / KC) {          // issue next chunk's loads
            const int off = (kc + 1) * KC;
            #pragma unroll
            for (int i = 0; i < 4; ++i) {
                int u = tid + i * 256;
                int r = u >> 3, c8 = (u & 7) * 8;
                const float* src = &X[(size_t)(row0 + r) * NC + off + c8];
                xp[i][0] = *(const float4*)(src);
                xp[i][1] = *(const float4*)(src + 4);
            }
            #pragma unroll
            for (int i = 0; i < 6; ++i) {
                int u = tid + i * 256;
                int r = u >> 3, c8 = (u & 7) * 8;
                wp[i] = *reinterpret_cast<const bf16x8*>(&Wt[r * NC + off + c8]);
            }
        }

        #pragma unroll
        for (int ks = 0; ks < 2; ++ks) {
            bf16x8 xf[2];
            #pragma unroll
            for (int tf = 0; tf < 2; ++tf)
                xf[tf] = *reinterpret_cast<const bf16x8*>(
                    &x_lds[wid * 32 + tf * 16 + l15][ks * 32 + lg * 8]);
            #pragma unroll
            for (int nf = 0; nf < 4; ++nf) {
                bf16x8 wq = *reinterpret_cast<const bf16x8*>(
                    &w_lds[nf * 16 + l15][ks * 32 + lg * 8]);
                bf16x8 wk = *reinterpret_cast<const bf16x8*>(
                    &w_lds[64 + nf * 16 + l15][ks * 32 + lg * 8]);
                bf16x8 wv = *reinterpret_cast<const bf16x8*>(
                    &w_lds[128 + nf * 16 + l15][ks * 32 + lg * 8]);
                #pragma unroll
                for (int tf = 0; tf < 2; ++tf) {
                    aQ[nf][tf] = __builtin_amdgcn_mfma_f32_16x16x32_bf16(wq, xf[tf], aQ[nf][tf], 0, 0, 0);
                    aK[nf][tf] = __builtin_amdgcn_mfma_f32_16x16x32_bf16(wk, xf[tf], aK[nf][tf], 0, 0, 0);
                    aV[tf][nf] = __builtin_amdgcn_mfma_f32_16x16x32_bf16(xf[tf], wv, aV[tf][nf], 0, 0, 0);
                }
            }
        }
    }

    const int b  = row0 >> 11;
    const int t0 = row0 & (NT - 1);
    #pragma unroll
    for (int nf = 0; nf < 4; ++nf)
        #pragma unroll
        for (int tf = 0; tf < 2; ++tf) {
            size_t o = (size_t)(row0 + wid * 32 + tf * 16 + l15) * NH + nf * 16 + lg * 4;
            short4 sq, sk;
            sq.x = f2b(aQ[nf][tf][0] * SCALE2); sq.y = f2b(aQ[nf][tf][1] * SCALE2);
            sq.z = f2b(aQ[nf][tf][2] * SCALE2); sq.w = f2b(aQ[nf][tf][3] * SCALE2);
            sk.x = f2b(aK[nf][tf][0]); sk.y = f2b(aK[nf][tf][1]);
            sk.z = f2b(aK[nf][tf][2]); sk.w = f2b(aK[nf][tf][3]);
            *reinterpret_cast<short4*>(&Q[o]) = sq;
            *reinterpret_cast<short4*>(&K[o]) = sk;
        }
    #pragma unroll
    for (int tf = 0; tf < 2; ++tf)
        #pragma unroll
        for (int df = 0; df < 4; ++df) {
            int d  = df * 16 + l15;
            int t4 = t0 + wid * 32 + tf * 16 + lg * 4;
            short4 sv;
            sv.x = f2b(aV[tf][df][0]); sv.y = f2b(aV[tf][df][1]);
            sv.z = f2b(aV[tf][df][2]); sv.w = f2b(aV[tf][df][3]);
            *reinterpret_cast<short4*>(&Vt[((size_t)b * NH + d) * NT + t4]) = sv;
        }
}

// ---------------------------------------------------------------------------
// Kernel B: mean over T of V per (batch, d) — degenerate-row fixup source.
// ---------------------------------------------------------------------------
__global__ __launch_bounds__(1024) void meanv_kernel(
    const __hip_bfloat16* __restrict__ Vt, float* __restrict__ MV)
{
    __shared__ float red[NH][17];
    const int b    = blockIdx.x;
    const int tid  = threadIdx.x;
    const int d    = tid >> 4;
    const int part = tid & 15;
    const __hip_bfloat16* row = Vt + ((size_t)b * NH + d) * NT;
    float s = 0.f;
    for (int t = part * 128; t < part * 128 + 128; t += 8) {
        bf16x8 v = *reinterpret_cast<const bf16x8*>(&row[t]);
        #pragma unroll
        for (int j = 0; j < 8; ++j) s += b2f(v[j]);
    }
    red[d][part] = s;
    __syncthreads();
    if (part == 0) {
        float tot = 0.f;
        #pragma unroll
        for (int i = 0; i < 16; ++i) tot += red[d][i];
        MV[b * NH + d] = tot * (1.0f / NT);
    }
}

// ---------------------------------------------------------------------------
// Online-softmax step: DEFER-MAX (THR=8, exp2 domain) + per-lane PARTIAL l.
// (verified round 10)
// ---------------------------------------------------------------------------
template<bool CAUSAL>
static __device__ inline void sm_step(
    int q, int k0, const int (&koff)[4],
    const f32x4 (&s)[4], float& m_r, float& l_r,
    bool& resc, float& al, bf16x8& pb0, bf16x8& pb1)
{
    float y[4][4];
    #pragma unroll
    for (int jt = 0; jt < 4; ++jt)
        #pragma unroll
        for (int r = 0; r < 4; ++r) {
            float v = s[jt][r];
            if (CAUSAL && (k0 + koff[jt] + r > q)) v = LNEG;
            y[jt][r] = v;
        }
    float pmax = y[0][0];
    #pragma unroll
    for (int jt = 0; jt < 4; ++jt)
        #pragma unroll
        for (int r = 0; r < 4; ++r) pmax = fmaxf(pmax, y[jt][r]);

    resc = __any(pmax > m_r + 8.0f);       // wave-uniform decision
    al   = 1.0f;
    if (resc) {                            // rare: full cross-lane max reduce
        float tm = fmaxf(pmax, __shfl_xor(pmax, 16));
        tm = fmaxf(tm, __shfl_xor(tm, 32));
        const float mnew = fmaxf(m_r, tm);
        al  = __builtin_amdgcn_exp2f(m_r - mnew);
        m_r = mnew;
        l_r *= al;
    }

    float p[4][4], rs = 0.f;
    #pragma unroll
    for (int jt = 0; jt < 4; ++jt)
        #pragma unroll
        for (int r = 0; r < 4; ++r) {
            p[jt][r] = __builtin_amdgcn_exp2f(y[jt][r] - m_r);
            rs += p[jt][r];
        }
    l_r += rs;                             // per-lane partial (reduced in epilogue)
    #pragma unroll
    for (int r = 0; r < 4; ++r) {
        pb0[r]     = f2b(p[0][r]);
        pb0[4 + r] = f2b(p[1][r]);
        pb1[r]     = f2b(p[2][r]);
        pb1[4 + r] = f2b(p[3][r]);
    }
}

// ---------------------------------------------------------------------------
// Kernel C: swapped-operand bf16 MFMA flash attention, SINGLE q-tile blocks.
// Grid 1024 (one q-tile each), longest-first dispatch -> 4 blocks/CU,
// 4 waves/SIMD (2x round-11 TLP; the r11 pairing was latency-bound at
// 2 waves/SIMD). All fragment maps / XOR swizzles / DMA staging / softmax
// byte-identical to the verified round-10/11 kernel; pair (B) state removed.
// ---------------------------------------------------------------------------
__global__ __launch_bounds__(256, 4) void attn_kernel(
    const __hip_bfloat16* __restrict__ Q, const __hip_bfloat16* __restrict__ K,
    const __hip_bfloat16* __restrict__ Vt, const float* __restrict__ Bias,
    const float* __restrict__ MV, float* __restrict__ Out)
{
    __shared__ __hip_bfloat16 k_lds[2][KB][NH];    // 2 x 8KB, row key col d
    __shared__ __hip_bfloat16 vt_lds[2][NH][KB];   // 2 x 8KB, row d col key

    const int bid  = blockIdx.x;                   // 1024 blocks
    const int xcd  = bid & 7;
    const int slot = bid >> 3;                     // 0..127
    const int b    = xcd * 4 + (slot >> 5);        // 4 batches per XCD
    const int qg   = 31 - (slot & 31);             // longest-first dispatch

    const int tid  = threadIdx.x;
    const int wid  = tid >> 6;
    const int lane = tid & 63;
    const int l15  = lane & 15;
    const int lg   = lane >> 4;

    const __hip_bfloat16* Kg = K  + (size_t)b * NT * NH;
    const __hip_bfloat16* Vg = Vt + (size_t)b * NH * NT;
    const float* Bb = Bias + b * NT;

    const int q = qg * QB + wid * 16 + l15;        // this lane's query row
    bf16x8 qf0, qf1;
    {
        const __hip_bfloat16* Qr = Q + ((size_t)b * NT + q) * NH;
        qf0 = *reinterpret_cast<const bf16x8*>(&Qr[lg * 8]);
        qf1 = *reinterpret_cast<const bf16x8*>(&Qr[lg * 8 + 32]);
    }

    f32x4 o_acc[4];
    #pragma unroll
    for (int dt = 0; dt < 4; ++dt) o_acc[dt] = (f32x4){0.f,0.f,0.f,0.f};
    float m_r = -3.0e38f, l_r = 0.f;

    // fragment addressing (round-3 verified key map + round-4 XOR swizzle)
    int kr[4], koff[4];
    #pragma unroll
    for (int jt = 0; jt < 4; ++jt) {
        kr[jt]   = ((jt & 2) << 4) | ((l15 >> 2) << 3) | ((jt & 1) << 2) | (l15 & 3);
        koff[jt] = ((jt & 2) << 4) | (lg << 3) | ((jt & 1) << 2);
    }
    const int swk  = (l15 & 3) | (((l15 >> 2) & 1) << 2);  // sw(kr), jt-invariant
    const int swv  = (l15 & 3) | (((l15 >> 3) & 1) << 2);  // sw(vr), dt-invariant
    const int kch0 = ((lg ^ swk) & 7) * 8;
    const int vch0 = ((lg ^ swv) & 7) * 8;

    // DMA staging coords (verified rounds 6/7): LDS dest linear, source chunk
    // pre-swizzled: sch = (lane&7) ^ sw(row), sw(row)=(row&3)|(((row>>3)&1)<<2)
    int srowL[2], schL[2];
    #pragma unroll
    for (int i = 0; i < 2; ++i) {
        const int ci  = wid * 2 + i;
        srowL[i] = ci * 8 + (lane >> 3);
        const int sw = ((lane >> 3) & 3) | ((ci & 1) << 2);
        schL[i]  = ((lane & 7) ^ sw) * 8;
    }

    #define STAGE(buf, kt_) do {                                              \
        const int _k0 = (kt_) * KB;                                           \
        _Pragma("unroll")                                                     \
        for (int i = 0; i < 2; ++i) {                                         \
            dma16(Kg + (size_t)(_k0 + srowL[i]) * NH + schL[i],               \
                  &k_lds[buf][(wid * 2 + i) * 8][0]);                         \
            dma16(Vg + (size_t)srowL[i] * NT + _k0 + schL[i],                 \
                  &vt_lds[buf][(wid * 2 + i) * 8][0]);                        \
        }                                                                     \
    } while (0)

    STAGE(0, 0);
    int cur = 0;

    // bias double-buffer (round 11): C-init loads prefetch one tile ahead
    f32x4 bias_cur[4], bias_nxt[4];
    #pragma unroll
    for (int jt = 0; jt < 4; ++jt)
        bias_cur[jt] = *reinterpret_cast<const f32x4*>(&Bb[koff[jt]]);

    for (int kt = 0; kt <= qg; ++kt) {
        asm volatile("s_waitcnt vmcnt(0)" ::: "memory");  // DMA of buf[cur] done
        __syncthreads();
        if (kt < qg) {
            STAGE(cur ^ 1, kt + 1);                       // overlaps compute
            const int kn = (kt + 1) * KB;
            #pragma unroll
            for (int jt = 0; jt < 4; ++jt)
                bias_nxt[jt] = *reinterpret_cast<const f32x4*>(&Bb[kn + koff[jt]]);
        }

        const int k0 = kt * KB;

        // ---- QK^T (C-init = bias) ----
        f32x4 s[4];
        __builtin_amdgcn_s_setprio(1);
        #pragma unroll
        for (int jt = 0; jt < 4; ++jt) {
            bf16x8 kfa = *reinterpret_cast<const bf16x8*>(&k_lds[cur][kr[jt]][kch0]);
            bf16x8 kfb = *reinterpret_cast<const bf16x8*>(&k_lds[cur][kr[jt]][kch0 ^ 32]);
            s[jt] = __builtin_amdgcn_mfma_f32_16x16x32_bf16(kfa, qf0, bias_cur[jt], 0, 0, 0);
            s[jt] = __builtin_amdgcn_mfma_f32_16x16x32_bf16(kfb, qf1, s[jt], 0, 0, 0);
        }
        __builtin_amdgcn_s_setprio(0);

        bool resc = false;
        float al = 1.f;
        bf16x8 pb0, pb1;
        if (kt == qg) sm_step<true >(q, k0, koff, s, m_r, l_r, resc, al, pb0, pb1);
        else          sm_step<false>(q, k0, koff, s, m_r, l_r, resc, al, pb0, pb1);

        // ---- rare rescale, outside the MFMA loop (wave-uniform branch) ----
        if (resc) {
            #pragma unroll
            for (int dt = 0; dt < 4; ++dt)
                #pragma unroll
                for (int r = 0; r < 4; ++r) o_acc[dt][r] *= al;
        }

        // ---- PV (branch-free MFMAs) ----
        __builtin_amdgcn_s_setprio(1);
        #pragma unroll
        for (int dt = 0; dt < 4; ++dt) {
            bf16x8 vfa = *reinterpret_cast<const bf16x8*>(&vt_lds[cur][dt * 16 + l15][vch0]);
            bf16x8 vfb = *reinterpret_cast<const bf16x8*>(&vt_lds[cur][dt * 16 + l15][vch0 ^ 32]);
            o_acc[dt] = __builtin_amdgcn_mfma_f32_16x16x32_bf16(vfa, pb0, o_acc[dt], 0, 0, 0);
            o_acc[dt] = __builtin_amdgcn_mfma_f32_16x16x32_bf16(vfb, pb1, o_acc[dt], 0, 0, 0);
        }
        __builtin_amdgcn_s_setprio(0);

        #pragma unroll
        for (int jt = 0; jt < 4; ++jt) bias_cur[jt] = bias_nxt[jt];  // static swap
        cur ^= 1;
    }
    #undef STAGE

    // ---- epilogue: reduce partial l (alpha is query-uniform -> exact),
    //      normalize; degenerate rows -> mean V ----
    float lt = l_r + __shfl_xor(l_r, 16); lt += __shfl_xor(lt, 32);

    const bool degen = (m_r <= -5.0e8f);
    const float inv  = degen ? 0.f : 1.0f / lt;
    float* Or = Out + ((size_t)b * NT + q) * NH;
    #pragma unroll
    for (int dt = 0; dt < 4; ++dt) {
        float4 ov;
        if (degen) {
            ov = *reinterpret_cast<const float4*>(&MV[b * NH + dt * 16 + lg * 4]);
        } else {
            ov.x = o_acc[dt][0] * inv; ov.y = o_acc[dt][1] * inv;
            ov.z = o_acc[dt][2] * inv; ov.w = o_acc[dt][3] * inv;
        }
        *reinterpret_cast<float4*>(&Or[dt * 16 + lg * 4]) = ov;
    }
}

// ---------------------------------------------------------------------------
extern "C" void kernel_launch(void* const* d_in, const int* in_sizes, int n_in,
                              void* d_out, int out_size, void* d_ws, size_t ws_size,
                              hipStream_t stream)
{
    const float* X  = (const float*)d_in[0];   // q_input (B,T,C) fp32
    const float* Wq = (const float*)d_in[1];
    const float* Wk = (const float*)d_in[2];
    const float* Wv = (const float*)d_in[3];
    const int*   M  = (const int*)d_in[4];     // attn_mask (B,T) int32
    float* out = (float*)d_out;                // (B,T,HS) fp32

    __hip_bfloat16* Qp = (__hip_bfloat16*)d_ws;
    __hip_bfloat16* Kp = Qp + (size_t)NB * NT * NH;
    __hip_bfloat16* Vp = Kp + (size_t)NB * NT * NH;
    float* MVp = (float*)(Vp + (size_t)NB * NT * NH);
    __hip_bfloat16* Wtp = (__hip_bfloat16*)(MVp + NB * NH);
    float* Biasp = (float*)(Wtp + 192 * NC);

    prep_kernel<<<448, 256, 0, stream>>>(Wq, Wk, Wv, M, Wtp, Biasp);
    qkv_kernel<<<NB * NT / MT, 256, 0, stream>>>(X, Wtp, Qp, Kp, Vp);
    meanv_kernel<<<NB, 1024, 0, stream>>>(Vp, MVp);
    attn_kernel<<<1024, 256, 0, stream>>>(Qp, Kp, Vp, Biasp, MVp, out);
}

// Round 13
// 75.779 us; speedup vs baseline: 1.1781x; 1.1781x over previous
//
#include <hip/hip_runtime.h>
#include <hip/hip_bf16.h>

// Problem constants (Head_60421599920770): B=32, T=2048, C=256, HS=64
#define NB 32
#define NT 2048
#define NC 256
#define NH 64
#define QB 64
#define KB 64
#define MT 128   // qkv M-tile rows per block
#define KC 64    // qkv K-chunk

typedef __attribute__((ext_vector_type(8))) short bf16x8;   // 8 bf16 = 4 VGPRs
typedef __attribute__((ext_vector_type(4))) float f32x4;    // MFMA C/D

static constexpr float SCALE2 = 0.18033688011112042f;  // HS^-0.5 * log2(e)
static constexpr float LNEG   = -1e9f;

static __device__ inline short f2b(float x) {
    __hip_bfloat16 h = __float2bfloat16(x);
    return *reinterpret_cast<short*>(&h);
}
static __device__ inline float b2f(short s) {
    unsigned int u = ((unsigned int)(unsigned short)s) << 16;
    float f; __builtin_memcpy(&f, &u, 4); return f;
}

// async global->LDS DMA, 16B per lane; LDS dest = wave-uniform base + lane*16
static __device__ inline void dma16(const __hip_bfloat16* g, __hip_bfloat16* l) {
    __builtin_amdgcn_global_load_lds(
        (const __attribute__((address_space(1))) unsigned int*)g,
        (__attribute__((address_space(3))) unsigned int*)l, 16, 0, 0);
}

// ---------------------------------------------------------------------------
// Merged prep: blocks 0-191 transpose W (Wt[n][k] bf16, n: Q|K|V cols);
// blocks 192-447 build Bias[b][t] = mask ? 0 : -1e9; block 448 zeros MV
// (qkv accumulates the V-mean into it with atomics).
// ---------------------------------------------------------------------------
__global__ __launch_bounds__(256) void prep_kernel(
    const float* __restrict__ Wq, const float* __restrict__ Wk,
    const float* __restrict__ Wv, const int* __restrict__ M,
    __hip_bfloat16* __restrict__ Wt, float* __restrict__ Bias,
    float* __restrict__ MV)
{
    const int n = blockIdx.x;
    if (n < 192) {
        const int k = threadIdx.x;           // 0..255
        const float* Wm = (n < 64) ? Wq : ((n < 128) ? Wk : Wv);
        Wt[n * NC + k] = __float2bfloat16(Wm[k * NH + (n & 63)]);
    } else if (n < 448) {
        const int i = (n - 192) * 256 + threadIdx.x;
        Bias[i] = M[i] ? 0.f : LNEG;
    } else {
        #pragma unroll
        for (int j = 0; j < 8; ++j) MV[threadIdx.x * 8 + j] = 0.f;
    }
}

// ---------------------------------------------------------------------------
// QKV projection as bf16 MFMA GEMM (verified round 2) + T14 register
// prefetch (verified round 11) + FUSED V-mean: per-lane reduction of the aV
// accumulators + atomicAdd into MV (replaces the meanv kernel; MV zeroed by
// prep). MV feeds the degenerate-row fixup in attn.
// ---------------------------------------------------------------------------
__global__ __launch_bounds__(256, 2) void qkv_kernel(
    const float* __restrict__ X, const __hip_bfloat16* __restrict__ Wt,
    __hip_bfloat16* __restrict__ Q, __hip_bfloat16* __restrict__ K,
    __hip_bfloat16* __restrict__ Vt, float* __restrict__ MV)
{
    __shared__ __hip_bfloat16 x_lds[MT][KC + 8];
    __shared__ __hip_bfloat16 w_lds[192][KC + 8];

    const int row0 = blockIdx.x * MT;
    const int tid  = threadIdx.x;
    const int wid  = tid >> 6;
    const int lane = tid & 63;
    const int l15  = lane & 15;
    const int lg   = lane >> 4;

    f32x4 aQ[4][2], aK[4][2], aV[2][4];
    #pragma unroll
    for (int i = 0; i < 4; ++i)
        #pragma unroll
        for (int j = 0; j < 2; ++j) {
            aQ[i][j] = (f32x4){0.f,0.f,0.f,0.f};
            aK[i][j] = (f32x4){0.f,0.f,0.f,0.f};
            aV[j][i] = (f32x4){0.f,0.f,0.f,0.f};
        }

    // ---- prefetch chunk 0 into registers ----
    float4 xp[4][2];
    bf16x8 wp[6];
    #pragma unroll
    for (int i = 0; i < 4; ++i) {
        int u = tid + i * 256;
        int r = u >> 3, c8 = (u & 7) * 8;
        const float* src = &X[(size_t)(row0 + r) * NC + c8];
        xp[i][0] = *(const float4*)(src);
        xp[i][1] = *(const float4*)(src + 4);
    }
    #pragma unroll
    for (int i = 0; i < 6; ++i) {
        int u = tid + i * 256;
        int r = u >> 3, c8 = (u & 7) * 8;
        wp[i] = *reinterpret_cast<const bf16x8*>(&Wt[r * NC + c8]);
    }

    for (int kc = 0; kc < NC / KC; ++kc) {
        __syncthreads();                 // previous chunk fully consumed
        #pragma unroll
        for (int i = 0; i < 4; ++i) {
            int u = tid + i * 256;
            int r = u >> 3, c8 = (u & 7) * 8;
            bf16x8 o;
            o[0]=f2b(xp[i][0].x); o[1]=f2b(xp[i][0].y);
            o[2]=f2b(xp[i][0].z); o[3]=f2b(xp[i][0].w);
            o[4]=f2b(xp[i][1].x); o[5]=f2b(xp[i][1].y);
            o[6]=f2b(xp[i][1].z); o[7]=f2b(xp[i][1].w);
            *reinterpret_cast<bf16x8*>(&x_lds[r][c8]) = o;
        }
        #pragma unroll
        for (int i = 0; i < 6; ++i) {
            int u = tid + i * 256;
            int r = u >> 3, c8 = (u & 7) * 8;
            *reinterpret_cast<bf16x8*>(&w_lds[r][c8]) = wp[i];
        }
        __syncthreads();

        if (kc + 1 < NC / KC) {          // issue next chunk's loads
            const int off = (kc + 1) * KC;
            #pragma unroll
            for (int i = 0; i < 4; ++i) {
                int u = tid + i * 256;
                int r = u >> 3, c8 = (u & 7) * 8;
                const float* src = &X[(size_t)(row0 + r) * NC + off + c8];
                xp[i][0] = *(const float4*)(src);
                xp[i][1] = *(const float4*)(src + 4);
            }
            #pragma unroll
            for (int i = 0; i < 6; ++i) {
                int u = tid + i * 256;
                int r = u >> 3, c8 = (u & 7) * 8;
                wp[i] = *reinterpret_cast<const bf16x8*>(&Wt[r * NC + off + c8]);
            }
        }

        #pragma unroll
        for (int ks = 0; ks < 2; ++ks) {
            bf16x8 xf[2];
            #pragma unroll
            for (int tf = 0; tf < 2; ++tf)
                xf[tf] = *reinterpret_cast<const bf16x8*>(
                    &x_lds[wid * 32 + tf * 16 + l15][ks * 32 + lg * 8]);
            #pragma unroll
            for (int nf = 0; nf < 4; ++nf) {
                bf16x8 wq = *reinterpret_cast<const bf16x8*>(
                    &w_lds[nf * 16 + l15][ks * 32 + lg * 8]);
                bf16x8 wk = *reinterpret_cast<const bf16x8*>(
                    &w_lds[64 + nf * 16 + l15][ks * 32 + lg * 8]);
                bf16x8 wv = *reinterpret_cast<const bf16x8*>(
                    &w_lds[128 + nf * 16 + l15][ks * 32 + lg * 8]);
                #pragma unroll
                for (int tf = 0; tf < 2; ++tf) {
                    aQ[nf][tf] = __builtin_amdgcn_mfma_f32_16x16x32_bf16(wq, xf[tf], aQ[nf][tf], 0, 0, 0);
                    aK[nf][tf] = __builtin_amdgcn_mfma_f32_16x16x32_bf16(wk, xf[tf], aK[nf][tf], 0, 0, 0);
                    aV[tf][nf] = __builtin_amdgcn_mfma_f32_16x16x32_bf16(xf[tf], wv, aV[tf][nf], 0, 0, 0);
                }
            }
        }
    }

    const int b  = row0 >> 11;
    const int t0 = row0 & (NT - 1);
    #pragma unroll
    for (int nf = 0; nf < 4; ++nf)
        #pragma unroll
        for (int tf = 0; tf < 2; ++tf) {
            size_t o = (size_t)(row0 + wid * 32 + tf * 16 + l15) * NH + nf * 16 + lg * 4;
            short4 sq, sk;
            sq.x = f2b(aQ[nf][tf][0] * SCALE2); sq.y = f2b(aQ[nf][tf][1] * SCALE2);
            sq.z = f2b(aQ[nf][tf][2] * SCALE2); sq.w = f2b(aQ[nf][tf][3] * SCALE2);
            sk.x = f2b(aK[nf][tf][0]); sk.y = f2b(aK[nf][tf][1]);
            sk.z = f2b(aK[nf][tf][2]); sk.w = f2b(aK[nf][tf][3]);
            *reinterpret_cast<short4*>(&Q[o]) = sq;
            *reinterpret_cast<short4*>(&K[o]) = sk;
        }
    #pragma unroll
    for (int tf = 0; tf < 2; ++tf)
        #pragma unroll
        for (int df = 0; df < 4; ++df) {
            int d  = df * 16 + l15;
            int t4 = t0 + wid * 32 + tf * 16 + lg * 4;
            short4 sv;
            sv.x = f2b(aV[tf][df][0]); sv.y = f2b(aV[tf][df][1]);
            sv.z = f2b(aV[tf][df][2]); sv.w = f2b(aV[tf][df][3]);
            *reinterpret_cast<short4*>(&Vt[((size_t)b * NH + d) * NT + t4]) = sv;
        }

    // ---- fused V-mean: lane holds 8 t-rows of V for d = df*16+l15 ----
    #pragma unroll
    for (int df = 0; df < 4; ++df) {
        float s = 0.f;
        #pragma unroll
        for (int tf = 0; tf < 2; ++tf)
            #pragma unroll
            for (int r = 0; r < 4; ++r) s += aV[tf][df][r];
        s += __shfl_xor(s, 16);              // reduce over lg (same l15)
        s += __shfl_xor(s, 32);
        if (lg == 0)
            atomicAdd(&MV[b * NH + df * 16 + l15], s * (1.0f / NT));
    }
}

// ---------------------------------------------------------------------------
// Online-softmax step: DEFER-MAX (THR=8, exp2 domain) + per-lane PARTIAL l.
// (verified round 10)
// ---------------------------------------------------------------------------
template<bool CAUSAL>
static __device__ inline void sm_step(
    int q, int k0, const int (&koff)[4],
    const f32x4 (&s)[4], float& m_r, float& l_r,
    bool& resc, float& al, bf16x8& pb0, bf16x8& pb1)
{
    float y[4][4];
    #pragma unroll
    for (int jt = 0; jt < 4; ++jt)
        #pragma unroll
        for (int r = 0; r < 4; ++r) {
            float v = s[jt][r];
            if (CAUSAL && (k0 + koff[jt] + r > q)) v = LNEG;
            y[jt][r] = v;
        }
    float pmax = y[0][0];
    #pragma unroll
    for (int jt = 0; jt < 4; ++jt)
        #pragma unroll
        for (int r = 0; r < 4; ++r) pmax = fmaxf(pmax, y[jt][r]);

    resc = __any(pmax > m_r + 8.0f);       // wave-uniform decision
    al   = 1.0f;
    if (resc) {                            // rare: full cross-lane max reduce
        float tm = fmaxf(pmax, __shfl_xor(pmax, 16));
        tm = fmaxf(tm, __shfl_xor(tm, 32));
        const float mnew = fmaxf(m_r, tm);
        al  = __builtin_amdgcn_exp2f(m_r - mnew);
        m_r = mnew;
        l_r *= al;
    }

    float p[4][4], rs = 0.f;
    #pragma unroll
    for (int jt = 0; jt < 4; ++jt)
        #pragma unroll
        for (int r = 0; r < 4; ++r) {
            p[jt][r] = __builtin_amdgcn_exp2f(y[jt][r] - m_r);
            rs += p[jt][r];
        }
    l_r += rs;                             // per-lane partial (reduced in epilogue)
    #pragma unroll
    for (int r = 0; r < 4; ++r) {
        pb0[r]     = f2b(p[0][r]);
        pb0[4 + r] = f2b(p[1][r]);
        pb1[r]     = f2b(p[2][r]);
        pb1[4 + r] = f2b(p[3][r]);
    }
}

// ---------------------------------------------------------------------------
// Kernel C: swapped-operand bf16 MFMA flash attention, PAIRED q-tiles —
// the round-10 verified configuration exactly (best measured: 51.7 us).
// 256 thr / 4 waves / 2 groups per wave; DMA double-buffered staging with
// source-side XOR swizzle; setprio; defer-max + partial-l softmax; direct
// per-tile bias loads (r11's bias double-buffer reverted: neutral-negative).
// ---------------------------------------------------------------------------
__global__ __launch_bounds__(256) void attn_kernel(
    const __hip_bfloat16* __restrict__ Q, const __hip_bfloat16* __restrict__ K,
    const __hip_bfloat16* __restrict__ Vt, const float* __restrict__ Bias,
    const float* __restrict__ MV, float* __restrict__ Out)
{
    __shared__ __hip_bfloat16 k_lds[2][KB][NH];    // 2 x 8KB, row key col d
    __shared__ __hip_bfloat16 vt_lds[2][NH][KB];   // 2 x 8KB, row d col key

    const int bid  = blockIdx.x;
    const int xcd  = bid & 7;
    const int slot = bid >> 3;                     // 0..63
    const int b    = xcd * 4 + (slot >> 4);        // 4 batches per XCD
    const int pi   = slot & 15;
    const int gA   = pi, gB = 31 - pi;             // paired q-tiles: uniform work

    const int tid  = threadIdx.x;
    const int wid  = tid >> 6;
    const int lane = tid & 63;
    const int l15  = lane & 15;
    const int lg   = lane >> 4;

    const __hip_bfloat16* Kg = K  + (size_t)b * NT * NH;
    const __hip_bfloat16* Vg = Vt + (size_t)b * NH * NT;
    const float* Bb = Bias + b * NT;

    const int qA = gA * QB + wid * 16 + l15;
    const int qB = gB * QB + wid * 16 + l15;
    bf16x8 qA0, qA1, qB0, qB1;
    {
        const __hip_bfloat16* Qr = Q + ((size_t)b * NT + qA) * NH;
        qA0 = *reinterpret_cast<const bf16x8*>(&Qr[lg * 8]);
        qA1 = *reinterpret_cast<const bf16x8*>(&Qr[lg * 8 + 32]);
        const __hip_bfloat16* Qs = Q + ((size_t)b * NT + qB) * NH;
        qB0 = *reinterpret_cast<const bf16x8*>(&Qs[lg * 8]);
        qB1 = *reinterpret_cast<const bf16x8*>(&Qs[lg * 8 + 32]);
    }

    f32x4 oA[4], oB[4];
    #pragma unroll
    for (int dt = 0; dt < 4; ++dt) {
        oA[dt] = (f32x4){0.f,0.f,0.f,0.f};
        oB[dt] = (f32x4){0.f,0.f,0.f,0.f};
    }
    float mA = -3.0e38f, lA = 0.f, mB = -3.0e38f, lB = 0.f;

    // fragment addressing (round-3 verified key map + round-4 XOR swizzle)
    int kr[4], koff[4];
    #pragma unroll
    for (int jt = 0; jt < 4; ++jt) {
        kr[jt]   = ((jt & 2) << 4) | ((l15 >> 2) << 3) | ((jt & 1) << 2) | (l15 & 3);
        koff[jt] = ((jt & 2) << 4) | (lg << 3) | ((jt & 1) << 2);
    }
    const int swk  = (l15 & 3) | (((l15 >> 2) & 1) << 2);  // sw(kr), jt-invariant
    const int swv  = (l15 & 3) | (((l15 >> 3) & 1) << 2);  // sw(vr), dt-invariant
    const int kch0 = ((lg ^ swk) & 7) * 8;
    const int vch0 = ((lg ^ swv) & 7) * 8;

    // DMA staging coords (verified rounds 6/7): LDS dest linear, source chunk
    // pre-swizzled: sch = (lane&7) ^ sw(row), sw(row)=(row&3)|(((row>>3)&1)<<2)
    int srowL[2], schL[2];
    #pragma unroll
    for (int i = 0; i < 2; ++i) {
        const int ci  = wid * 2 + i;
        srowL[i] = ci * 8 + (lane >> 3);
        const int sw = ((lane >> 3) & 3) | ((ci & 1) << 2);
        schL[i]  = ((lane & 7) ^ sw) * 8;
    }

    #define STAGE(buf, kt_) do {                                              \
        const int _k0 = (kt_) * KB;                                           \
        _Pragma("unroll")                                                     \
        for (int i = 0; i < 2; ++i) {                                         \
            dma16(Kg + (size_t)(_k0 + srowL[i]) * NH + schL[i],               \
                  &k_lds[buf][(wid * 2 + i) * 8][0]);                         \
            dma16(Vg + (size_t)srowL[i] * NT + _k0 + schL[i],                 \
                  &vt_lds[buf][(wid * 2 + i) * 8][0]);                        \
        }                                                                     \
    } while (0)

    STAGE(0, 0);
    int cur = 0;

    for (int kt = 0; kt <= gB; ++kt) {
        const int k0 = kt * KB;
        asm volatile("s_waitcnt vmcnt(0)" ::: "memory");  // DMA of buf[cur] done
        __syncthreads();
        if (kt < gB) STAGE(cur ^ 1, kt + 1);              // overlaps compute

        const bool aAct = (kt <= gA);

        f32x4 bias4[4];
        #pragma unroll
        for (int jt = 0; jt < 4; ++jt)
            bias4[jt] = *reinterpret_cast<const f32x4*>(&Bb[k0 + koff[jt]]);

        // ---- QK^T: shared K fragments feed both groups (C-init = bias) ----
        f32x4 sA[4], sB[4];
        __builtin_amdgcn_s_setprio(1);
        #pragma unroll
        for (int jt = 0; jt < 4; ++jt) {
            bf16x8 kfa = *reinterpret_cast<const bf16x8*>(&k_lds[cur][kr[jt]][kch0]);
            bf16x8 kfb = *reinterpret_cast<const bf16x8*>(&k_lds[cur][kr[jt]][kch0 ^ 32]);
            sB[jt] = __builtin_amdgcn_mfma_f32_16x16x32_bf16(kfa, qB0, bias4[jt], 0, 0, 0);
            sB[jt] = __builtin_amdgcn_mfma_f32_16x16x32_bf16(kfb, qB1, sB[jt], 0, 0, 0);
            if (aAct) {
                sA[jt] = __builtin_amdgcn_mfma_f32_16x16x32_bf16(kfa, qA0, bias4[jt], 0, 0, 0);
                sA[jt] = __builtin_amdgcn_mfma_f32_16x16x32_bf16(kfb, qA1, sA[jt], 0, 0, 0);
            }
        }
        __builtin_amdgcn_s_setprio(0);

        bool rescA = false, rescB = false;
        float alA = 1.f, alB = 1.f;
        bf16x8 pA0, pA1, pB0, pB1;
        if (kt == gB) sm_step<true >(qB, k0, koff, sB, mB, lB, rescB, alB, pB0, pB1);
        else          sm_step<false>(qB, k0, koff, sB, mB, lB, rescB, alB, pB0, pB1);
        if (aAct) {
            if (kt == gA) sm_step<true >(qA, k0, koff, sA, mA, lA, rescA, alA, pA0, pA1);
            else          sm_step<false>(qA, k0, koff, sA, mA, lA, rescA, alA, pA0, pA1);
        }

        // ---- rare rescale, OUTSIDE the MFMA loop (wave-uniform branches) ----
        if (rescB) {
            #pragma unroll
            for (int dt = 0; dt < 4; ++dt)
                #pragma unroll
                for (int r = 0; r < 4; ++r) oB[dt][r] *= alB;
        }
        if (rescA) {
            #pragma unroll
            for (int dt = 0; dt < 4; ++dt)
                #pragma unroll
                for (int r = 0; r < 4; ++r) oA[dt][r] *= alA;
        }

        // ---- PV: shared V fragments feed both groups (branch-free MFMAs) ----
        __builtin_amdgcn_s_setprio(1);
        #pragma unroll
        for (int dt = 0; dt < 4; ++dt) {
            bf16x8 vfa = *reinterpret_cast<const bf16x8*>(&vt_lds[cur][dt * 16 + l15][vch0]);
            bf16x8 vfb = *reinterpret_cast<const bf16x8*>(&vt_lds[cur][dt * 16 + l15][vch0 ^ 32]);
            oB[dt] = __builtin_amdgcn_mfma_f32_16x16x32_bf16(vfa, pB0, oB[dt], 0, 0, 0);
            oB[dt] = __builtin_amdgcn_mfma_f32_16x16x32_bf16(vfb, pB1, oB[dt], 0, 0, 0);
            if (aAct) {
                oA[dt] = __builtin_amdgcn_mfma_f32_16x16x32_bf16(vfa, pA0, oA[dt], 0, 0, 0);
                oA[dt] = __builtin_amdgcn_mfma_f32_16x16x32_bf16(vfb, pA1, oA[dt], 0, 0, 0);
            }
        }
        __builtin_amdgcn_s_setprio(0);
        cur ^= 1;
    }
    #undef STAGE

    // ---- epilogue: reduce partial l (alpha is query-uniform -> exact),
    //      normalize; degenerate rows -> mean V ----
    float lAt = lA + __shfl_xor(lA, 16); lAt += __shfl_xor(lAt, 32);
    float lBt = lB + __shfl_xor(lB, 16); lBt += __shfl_xor(lBt, 32);

    #pragma unroll
    for (int grp = 0; grp < 2; ++grp) {
        const int   q  = grp ? qB : qA;
        const float m  = grp ? mB : mA;
        const float l  = grp ? lBt : lAt;
        const f32x4* o = grp ? oB : oA;
        const bool degen = (m <= -5.0e8f);
        const float inv  = degen ? 0.f : 1.0f / l;
        float* Or = Out + ((size_t)b * NT + q) * NH;
        #pragma unroll
        for (int dt = 0; dt < 4; ++dt) {
            float4 ov;
            if (degen) {
                ov = *reinterpret_cast<const float4*>(&MV[b * NH + dt * 16 + lg * 4]);
            } else {
                ov.x = o[dt][0] * inv; ov.y = o[dt][1] * inv;
                ov.z = o[dt][2] * inv; ov.w = o[dt][3] * inv;
            }
            *reinterpret_cast<float4*>(&Or[dt * 16 + lg * 4]) = ov;
        }
    }
}

// ---------------------------------------------------------------------------
extern "C" void kernel_launch(void* const* d_in, const int* in_sizes, int n_in,
                              void* d_out, int out_size, void* d_ws, size_t ws_size,
                              hipStream_t stream)
{
    const float* X  = (const float*)d_in[0];   // q_input (B,T,C) fp32
    const float* Wq = (const float*)d_in[1];
    const float* Wk = (const float*)d_in[2];
    const float* Wv = (const float*)d_in[3];
    const int*   M  = (const int*)d_in[4];     // attn_mask (B,T) int32
    float* out = (float*)d_out;                // (B,T,HS) fp32

    __hip_bfloat16* Qp = (__hip_bfloat16*)d_ws;
    __hip_bfloat16* Kp = Qp + (size_t)NB * NT * NH;
    __hip_bfloat16* Vp = Kp + (size_t)NB * NT * NH;
    float* MVp = (float*)(Vp + (size_t)NB * NT * NH);
    __hip_bfloat16* Wtp = (__hip_bfloat16*)(MVp + NB * NH);
    float* Biasp = (float*)(Wtp + 192 * NC);

    prep_kernel<<<449, 256, 0, stream>>>(Wq, Wk, Wv, M, Wtp, Biasp, MVp);
    qkv_kernel<<<NB * NT / MT, 256, 0, stream>>>(X, Wtp, Qp, Kp, Vp, MVp);
    attn_kernel<<<512, 256, 0, stream>>>(Qp, Kp, Vp, Biasp, MVp, out);
}

// Round 14
// 72.863 us; speedup vs baseline: 1.2253x; 1.0400x over previous
//
#include <hip/hip_runtime.h>
#include <hip/hip_bf16.h>

// Problem constants (Head_60421599920770): B=32, T=2048, C=256, HS=64
#define NB 32
#define NT 2048
#define NC 256
#define NH 64
#define QB 64
#define KB 64
#define MT 128   // qkv M-tile rows per block
#define KC 64    // qkv K-chunk

typedef __attribute__((ext_vector_type(8))) short bf16x8;   // 8 bf16 = 4 VGPRs
typedef __attribute__((ext_vector_type(4))) float f32x4;    // MFMA C/D

static constexpr float SCALE2 = 0.18033688011112042f;  // HS^-0.5 * log2(e)
static constexpr float LNEG   = -1e9f;

static __device__ inline short f2b(float x) {
    __hip_bfloat16 h = __float2bfloat16(x);
    return *reinterpret_cast<short*>(&h);
}
static __device__ inline float b2f(short s) {
    unsigned int u = ((unsigned int)(unsigned short)s) << 16;
    float f; __builtin_memcpy(&f, &u, 4); return f;
}

// async global->LDS DMA, 16B per lane; LDS dest = wave-uniform base + lane*16
static __device__ inline void dma16(const __hip_bfloat16* g, __hip_bfloat16* l) {
    __builtin_amdgcn_global_load_lds(
        (const __attribute__((address_space(1))) unsigned int*)g,
        (__attribute__((address_space(3))) unsigned int*)l, 16, 0, 0);
}

// ---------------------------------------------------------------------------
// Merged prep: blocks 0-191 transpose W (Wt[n][k] bf16, n: Q|K|V cols);
// blocks 192-447 build Bias[b][t] = mask ? 0 : -1e9; block 448 zeros MV.
// ---------------------------------------------------------------------------
__global__ __launch_bounds__(256) void prep_kernel(
    const float* __restrict__ Wq, const float* __restrict__ Wk,
    const float* __restrict__ Wv, const int* __restrict__ M,
    __hip_bfloat16* __restrict__ Wt, float* __restrict__ Bias,
    float* __restrict__ MV)
{
    const int n = blockIdx.x;
    if (n < 192) {
        const int k = threadIdx.x;           // 0..255
        const float* Wm = (n < 64) ? Wq : ((n < 128) ? Wk : Wv);
        Wt[n * NC + k] = __float2bfloat16(Wm[k * NH + (n & 63)]);
    } else if (n < 448) {
        const int i = (n - 192) * 256 + threadIdx.x;
        Bias[i] = M[i] ? 0.f : LNEG;
    } else {
        #pragma unroll
        for (int j = 0; j < 8; ++j) MV[threadIdx.x * 8 + j] = 0.f;
    }
}

// ---------------------------------------------------------------------------
// QKV projection as bf16 MFMA GEMM (verified round 2) + T14 register
// prefetch (verified round 11) + fused V-mean (verified round 13).
// ---------------------------------------------------------------------------
__global__ __launch_bounds__(256, 2) void qkv_kernel(
    const float* __restrict__ X, const __hip_bfloat16* __restrict__ Wt,
    __hip_bfloat16* __restrict__ Q, __hip_bfloat16* __restrict__ K,
    __hip_bfloat16* __restrict__ Vt, float* __restrict__ MV)
{
    __shared__ __hip_bfloat16 x_lds[MT][KC + 8];
    __shared__ __hip_bfloat16 w_lds[192][KC + 8];

    const int row0 = blockIdx.x * MT;
    const int tid  = threadIdx.x;
    const int wid  = tid >> 6;
    const int lane = tid & 63;
    const int l15  = lane & 15;
    const int lg   = lane >> 4;

    f32x4 aQ[4][2], aK[4][2], aV[2][4];
    #pragma unroll
    for (int i = 0; i < 4; ++i)
        #pragma unroll
        for (int j = 0; j < 2; ++j) {
            aQ[i][j] = (f32x4){0.f,0.f,0.f,0.f};
            aK[i][j] = (f32x4){0.f,0.f,0.f,0.f};
            aV[j][i] = (f32x4){0.f,0.f,0.f,0.f};
        }

    // ---- prefetch chunk 0 into registers ----
    float4 xp[4][2];
    bf16x8 wp[6];
    #pragma unroll
    for (int i = 0; i < 4; ++i) {
        int u = tid + i * 256;
        int r = u >> 3, c8 = (u & 7) * 8;
        const float* src = &X[(size_t)(row0 + r) * NC + c8];
        xp[i][0] = *(const float4*)(src);
        xp[i][1] = *(const float4*)(src + 4);
    }
    #pragma unroll
    for (int i = 0; i < 6; ++i) {
        int u = tid + i * 256;
        int r = u >> 3, c8 = (u & 7) * 8;
        wp[i] = *reinterpret_cast<const bf16x8*>(&Wt[r * NC + c8]);
    }

    for (int kc = 0; kc < NC / KC; ++kc) {
        __syncthreads();                 // previous chunk fully consumed
        #pragma unroll
        for (int i = 0; i < 4; ++i) {
            int u = tid + i * 256;
            int r = u >> 3, c8 = (u & 7) * 8;
            bf16x8 o;
            o[0]=f2b(xp[i][0].x); o[1]=f2b(xp[i][0].y);
            o[2]=f2b(xp[i][0].z); o[3]=f2b(xp[i][0].w);
            o[4]=f2b(xp[i][1].x); o[5]=f2b(xp[i][1].y);
            o[6]=f2b(xp[i][1].z); o[7]=f2b(xp[i][1].w);
            *reinterpret_cast<bf16x8*>(&x_lds[r][c8]) = o;
        }
        #pragma unroll
        for (int i = 0; i < 6; ++i) {
            int u = tid + i * 256;
            int r = u >> 3, c8 = (u & 7) * 8;
            *reinterpret_cast<bf16x8*>(&w_lds[r][c8]) = wp[i];
        }
        __syncthreads();

        if (kc + 1 < NC / KC) {          // issue next chunk's loads
            const int off = (kc + 1) * KC;
            #pragma unroll
            for (int i = 0; i < 4; ++i) {
                int u = tid + i * 256;
                int r = u >> 3, c8 = (u & 7) * 8;
                const float* src = &X[(size_t)(row0 + r) * NC + off + c8];
                xp[i][0] = *(const float4*)(src);
                xp[i][1] = *(const float4*)(src + 4);
            }
            #pragma unroll
            for (int i = 0; i < 6; ++i) {
                int u = tid + i * 256;
                int r = u >> 3, c8 = (u & 7) * 8;
                wp[i] = *reinterpret_cast<const bf16x8*>(&Wt[r * NC + off + c8]);
            }
        }

        #pragma unroll
        for (int ks = 0; ks < 2; ++ks) {
            bf16x8 xf[2];
            #pragma unroll
            for (int tf = 0; tf < 2; ++tf)
                xf[tf] = *reinterpret_cast<const bf16x8*>(
                    &x_lds[wid * 32 + tf * 16 + l15][ks * 32 + lg * 8]);
            #pragma unroll
            for (int nf = 0; nf < 4; ++nf) {
                bf16x8 wq = *reinterpret_cast<const bf16x8*>(
                    &w_lds[nf * 16 + l15][ks * 32 + lg * 8]);
                bf16x8 wk = *reinterpret_cast<const bf16x8*>(
                    &w_lds[64 + nf * 16 + l15][ks * 32 + lg * 8]);
                bf16x8 wv = *reinterpret_cast<const bf16x8*>(
                    &w_lds[128 + nf * 16 + l15][ks * 32 + lg * 8]);
                #pragma unroll
                for (int tf = 0; tf < 2; ++tf) {
                    aQ[nf][tf] = __builtin_amdgcn_mfma_f32_16x16x32_bf16(wq, xf[tf], aQ[nf][tf], 0, 0, 0);
                    aK[nf][tf] = __builtin_amdgcn_mfma_f32_16x16x32_bf16(wk, xf[tf], aK[nf][tf], 0, 0, 0);
                    aV[tf][nf] = __builtin_amdgcn_mfma_f32_16x16x32_bf16(xf[tf], wv, aV[tf][nf], 0, 0, 0);
                }
            }
        }
    }

    const int b  = row0 >> 11;
    const int t0 = row0 & (NT - 1);
    #pragma unroll
    for (int nf = 0; nf < 4; ++nf)
        #pragma unroll
        for (int tf = 0; tf < 2; ++tf) {
            size_t o = (size_t)(row0 + wid * 32 + tf * 16 + l15) * NH + nf * 16 + lg * 4;
            short4 sq, sk;
            sq.x = f2b(aQ[nf][tf][0] * SCALE2); sq.y = f2b(aQ[nf][tf][1] * SCALE2);
            sq.z = f2b(aQ[nf][tf][2] * SCALE2); sq.w = f2b(aQ[nf][tf][3] * SCALE2);
            sk.x = f2b(aK[nf][tf][0]); sk.y = f2b(aK[nf][tf][1]);
            sk.z = f2b(aK[nf][tf][2]); sk.w = f2b(aK[nf][tf][3]);
            *reinterpret_cast<short4*>(&Q[o]) = sq;
            *reinterpret_cast<short4*>(&K[o]) = sk;
        }
    #pragma unroll
    for (int tf = 0; tf < 2; ++tf)
        #pragma unroll
        for (int df = 0; df < 4; ++df) {
            int d  = df * 16 + l15;
            int t4 = t0 + wid * 32 + tf * 16 + lg * 4;
            short4 sv;
            sv.x = f2b(aV[tf][df][0]); sv.y = f2b(aV[tf][df][1]);
            sv.z = f2b(aV[tf][df][2]); sv.w = f2b(aV[tf][df][3]);
            *reinterpret_cast<short4*>(&Vt[((size_t)b * NH + d) * NT + t4]) = sv;
        }

    // ---- fused V-mean: lane holds 8 t-rows of V for d = df*16+l15 ----
    #pragma unroll
    for (int df = 0; df < 4; ++df) {
        float s = 0.f;
        #pragma unroll
        for (int tf = 0; tf < 2; ++tf)
            #pragma unroll
            for (int r = 0; r < 4; ++r) s += aV[tf][df][r];
        s += __shfl_xor(s, 16);              // reduce over lg (same l15)
        s += __shfl_xor(s, 32);
        if (lg == 0)
            atomicAdd(&MV[b * NH + df * 16 + l15], s * (1.0f / NT));
    }
}

// ---------------------------------------------------------------------------
// Online-softmax step: rs-THRESHOLD defer-max + per-lane PARTIAL l.
// Softmax is shift-invariant, so the stale max is EXACT as long as values
// stay in range; we enforce p <= rs <= 2^8 (the same bound the old
// pmax>m+8 check gave) by testing the row-sum we already compute for l.
// Common path: 16 exp2 + adds + 1 cmp + ballot — the 16-fmax tree moved
// into the rare rescale branch. First-tile / all-masked / self-heal
// behavior identical (rs=inf triggers the branch).
// ---------------------------------------------------------------------------
template<bool CAUSAL>
static __device__ inline void sm_step(
    int q, int k0, const int (&koff)[4],
    const f32x4 (&s)[4], float& m_r, float& l_r,
    bool& resc, float& al, bf16x8& pb0, bf16x8& pb1)
{
    float y[4][4];
    #pragma unroll
    for (int jt = 0; jt < 4; ++jt)
        #pragma unroll
        for (int r = 0; r < 4; ++r) {
            float v = s[jt][r];
            if (CAUSAL && (k0 + koff[jt] + r > q)) v = LNEG;
            y[jt][r] = v;
        }

    float p[4][4], rs = 0.f;
    #pragma unroll
    for (int jt = 0; jt < 4; ++jt)
        #pragma unroll
        for (int r = 0; r < 4; ++r) {
            p[jt][r] = __builtin_amdgcn_exp2f(y[jt][r] - m_r);
            rs += p[jt][r];
        }

    resc = __any(rs > 256.0f);             // wave-uniform; p <= rs <= 2^8 if false
    al   = 1.0f;
    if (resc) {                            // rare: recover fresh max, recompute
        float pmax = y[0][0];
        #pragma unroll
        for (int jt = 0; jt < 4; ++jt)
            #pragma unroll
            for (int r = 0; r < 4; ++r) pmax = fmaxf(pmax, y[jt][r]);
        float tm = fmaxf(pmax, __shfl_xor(pmax, 16));
        tm = fmaxf(tm, __shfl_xor(tm, 32));
        const float mnew = fmaxf(m_r, tm);
        al  = __builtin_amdgcn_exp2f(m_r - mnew);
        m_r = mnew;
        l_r *= al;
        rs = 0.f;
        #pragma unroll
        for (int jt = 0; jt < 4; ++jt)
            #pragma unroll
            for (int r = 0; r < 4; ++r) {
                p[jt][r] = __builtin_amdgcn_exp2f(y[jt][r] - m_r);
                rs += p[jt][r];
            }
    }
    l_r += rs;                             // per-lane partial (reduced in epilogue)
    #pragma unroll
    for (int r = 0; r < 4; ++r) {
        pb0[r]     = f2b(p[0][r]);
        pb0[4 + r] = f2b(p[1][r]);
        pb1[r]     = f2b(p[2][r]);
        pb1[4 + r] = f2b(p[3][r]);
    }
}

// ---------------------------------------------------------------------------
// Kernel C: swapped-operand bf16 MFMA flash attention, PAIRED q-tiles
// (round-13 verified skeleton). This round: (a) STAGE issue moved AFTER the
// QK MFMA cluster so the 16KB LDS DMA burst doesn't collide with the QK
// ds_read burst; (b) rs-threshold softmax (fmax tree off the common path).
// ---------------------------------------------------------------------------
__global__ __launch_bounds__(256) void attn_kernel(
    const __hip_bfloat16* __restrict__ Q, const __hip_bfloat16* __restrict__ K,
    const __hip_bfloat16* __restrict__ Vt, const float* __restrict__ Bias,
    const float* __restrict__ MV, float* __restrict__ Out)
{
    __shared__ __hip_bfloat16 k_lds[2][KB][NH];    // 2 x 8KB, row key col d
    __shared__ __hip_bfloat16 vt_lds[2][NH][KB];   // 2 x 8KB, row d col key

    const int bid  = blockIdx.x;
    const int xcd  = bid & 7;
    const int slot = bid >> 3;                     // 0..63
    const int b    = xcd * 4 + (slot >> 4);        // 4 batches per XCD
    const int pi   = slot & 15;
    const int gA   = pi, gB = 31 - pi;             // paired q-tiles: uniform work

    const int tid  = threadIdx.x;
    const int wid  = tid >> 6;
    const int lane = tid & 63;
    const int l15  = lane & 15;
    const int lg   = lane >> 4;

    const __hip_bfloat16* Kg = K  + (size_t)b * NT * NH;
    const __hip_bfloat16* Vg = Vt + (size_t)b * NH * NT;
    const float* Bb = Bias + b * NT;

    const int qA = gA * QB + wid * 16 + l15;
    const int qB = gB * QB + wid * 16 + l15;
    bf16x8 qA0, qA1, qB0, qB1;
    {
        const __hip_bfloat16* Qr = Q + ((size_t)b * NT + qA) * NH;
        qA0 = *reinterpret_cast<const bf16x8*>(&Qr[lg * 8]);
        qA1 = *reinterpret_cast<const bf16x8*>(&Qr[lg * 8 + 32]);
        const __hip_bfloat16* Qs = Q + ((size_t)b * NT + qB) * NH;
        qB0 = *reinterpret_cast<const bf16x8*>(&Qs[lg * 8]);
        qB1 = *reinterpret_cast<const bf16x8*>(&Qs[lg * 8 + 32]);
    }

    f32x4 oA[4], oB[4];
    #pragma unroll
    for (int dt = 0; dt < 4; ++dt) {
        oA[dt] = (f32x4){0.f,0.f,0.f,0.f};
        oB[dt] = (f32x4){0.f,0.f,0.f,0.f};
    }
    float mA = -3.0e38f, lA = 0.f, mB = -3.0e38f, lB = 0.f;

    // fragment addressing (round-3 verified key map + round-4 XOR swizzle)
    int kr[4], koff[4];
    #pragma unroll
    for (int jt = 0; jt < 4; ++jt) {
        kr[jt]   = ((jt & 2) << 4) | ((l15 >> 2) << 3) | ((jt & 1) << 2) | (l15 & 3);
        koff[jt] = ((jt & 2) << 4) | (lg << 3) | ((jt & 1) << 2);
    }
    const int swk  = (l15 & 3) | (((l15 >> 2) & 1) << 2);  // sw(kr), jt-invariant
    const int swv  = (l15 & 3) | (((l15 >> 3) & 1) << 2);  // sw(vr), dt-invariant
    const int kch0 = ((lg ^ swk) & 7) * 8;
    const int vch0 = ((lg ^ swv) & 7) * 8;

    // DMA staging coords (verified rounds 6/7): LDS dest linear, source chunk
    // pre-swizzled: sch = (lane&7) ^ sw(row), sw(row)=(row&3)|(((row>>3)&1)<<2)
    int srowL[2], schL[2];
    #pragma unroll
    for (int i = 0; i < 2; ++i) {
        const int ci  = wid * 2 + i;
        srowL[i] = ci * 8 + (lane >> 3);
        const int sw = ((lane >> 3) & 3) | ((ci & 1) << 2);
        schL[i]  = ((lane & 7) ^ sw) * 8;
    }

    #define STAGE(buf, kt_) do {                                              \
        const int _k0 = (kt_) * KB;                                           \
        _Pragma("unroll")                                                     \
        for (int i = 0; i < 2; ++i) {                                         \
            dma16(Kg + (size_t)(_k0 + srowL[i]) * NH + schL[i],               \
                  &k_lds[buf][(wid * 2 + i) * 8][0]);                         \
            dma16(Vg + (size_t)srowL[i] * NT + _k0 + schL[i],                 \
                  &vt_lds[buf][(wid * 2 + i) * 8][0]);                        \
        }                                                                     \
    } while (0)

    STAGE(0, 0);
    int cur = 0;

    for (int kt = 0; kt <= gB; ++kt) {
        const int k0 = kt * KB;
        asm volatile("s_waitcnt vmcnt(0)" ::: "memory");  // DMA of buf[cur] done
        __syncthreads();

        const bool aAct = (kt <= gA);

        f32x4 bias4[4];
        #pragma unroll
        for (int jt = 0; jt < 4; ++jt)
            bias4[jt] = *reinterpret_cast<const f32x4*>(&Bb[k0 + koff[jt]]);

        // ---- QK^T: shared K fragments feed both groups (C-init = bias) ----
        f32x4 sA[4], sB[4];
        __builtin_amdgcn_s_setprio(1);
        #pragma unroll
        for (int jt = 0; jt < 4; ++jt) {
            bf16x8 kfa = *reinterpret_cast<const bf16x8*>(&k_lds[cur][kr[jt]][kch0]);
            bf16x8 kfb = *reinterpret_cast<const bf16x8*>(&k_lds[cur][kr[jt]][kch0 ^ 32]);
            sB[jt] = __builtin_amdgcn_mfma_f32_16x16x32_bf16(kfa, qB0, bias4[jt], 0, 0, 0);
            sB[jt] = __builtin_amdgcn_mfma_f32_16x16x32_bf16(kfb, qB1, sB[jt], 0, 0, 0);
            if (aAct) {
                sA[jt] = __builtin_amdgcn_mfma_f32_16x16x32_bf16(kfa, qA0, bias4[jt], 0, 0, 0);
                sA[jt] = __builtin_amdgcn_mfma_f32_16x16x32_bf16(kfb, qA1, sA[jt], 0, 0, 0);
            }
        }
        __builtin_amdgcn_s_setprio(0);

        // ---- stage next tile AFTER the QK read burst (LDS decollision) ----
        if (kt < gB) STAGE(cur ^ 1, kt + 1);

        bool rescA = false, rescB = false;
        float alA = 1.f, alB = 1.f;
        bf16x8 pA0, pA1, pB0, pB1;
        if (kt == gB) sm_step<true >(qB, k0, koff, sB, mB, lB, rescB, alB, pB0, pB1);
        else          sm_step<false>(qB, k0, koff, sB, mB, lB, rescB, alB, pB0, pB1);
        if (aAct) {
            if (kt == gA) sm_step<true >(qA, k0, koff, sA, mA, lA, rescA, alA, pA0, pA1);
            else          sm_step<false>(qA, k0, koff, sA, mA, lA, rescA, alA, pA0, pA1);
        }

        // ---- rare rescale, OUTSIDE the MFMA loop (wave-uniform branches) ----
        if (rescB) {
            #pragma unroll
            for (int dt = 0; dt < 4; ++dt)
                #pragma unroll
                for (int r = 0; r < 4; ++r) oB[dt][r] *= alB;
        }
        if (rescA) {
            #pragma unroll
            for (int dt = 0; dt < 4; ++dt)
                #pragma unroll
                for (int r = 0; r < 4; ++r) oA[dt][r] *= alA;
        }

        // ---- PV: shared V fragments feed both groups (branch-free MFMAs) ----
        __builtin_amdgcn_s_setprio(1);
        #pragma unroll
        for (int dt = 0; dt < 4; ++dt) {
            bf16x8 vfa = *reinterpret_cast<const bf16x8*>(&vt_lds[cur][dt * 16 + l15][vch0]);
            bf16x8 vfb = *reinterpret_cast<const bf16x8*>(&vt_lds[cur][dt * 16 + l15][vch0 ^ 32]);
            oB[dt] = __builtin_amdgcn_mfma_f32_16x16x32_bf16(vfa, pB0, oB[dt], 0, 0, 0);
            oB[dt] = __builtin_amdgcn_mfma_f32_16x16x32_bf16(vfb, pB1, oB[dt], 0, 0, 0);
            if (aAct) {
                oA[dt] = __builtin_amdgcn_mfma_f32_16x16x32_bf16(vfa, pA0, oA[dt], 0, 0, 0);
                oA[dt] = __builtin_amdgcn_mfma_f32_16x16x32_bf16(vfb, pA1, oA[dt], 0, 0, 0);
            }
        }
        __builtin_amdgcn_s_setprio(0);
        cur ^= 1;
    }
    #undef STAGE

    // ---- epilogue: reduce partial l (alpha is query-uniform -> exact),
    //      normalize; degenerate rows -> mean V ----
    float lAt = lA + __shfl_xor(lA, 16); lAt += __shfl_xor(lAt, 32);
    float lBt = lB + __shfl_xor(lB, 16); lBt += __shfl_xor(lBt, 32);

    #pragma unroll
    for (int grp = 0; grp < 2; ++grp) {
        const int   q  = grp ? qB : qA;
        const float m  = grp ? mB : mA;
        const float l  = grp ? lBt : lAt;
        const f32x4* o = grp ? oB : oA;
        const bool degen = (m <= -5.0e8f);
        const float inv  = degen ? 0.f : 1.0f / l;
        float* Or = Out + ((size_t)b * NT + q) * NH;
        #pragma unroll
        for (int dt = 0; dt < 4; ++dt) {
            float4 ov;
            if (degen) {
                ov = *reinterpret_cast<const float4*>(&MV[b * NH + dt * 16 + lg * 4]);
            } else {
                ov.x = o[dt][0] * inv; ov.y = o[dt][1] * inv;
                ov.z = o[dt][2] * inv; ov.w = o[dt][3] * inv;
            }
            *reinterpret_cast<float4*>(&Or[dt * 16 + lg * 4]) = ov;
        }
    }
}

// ---------------------------------------------------------------------------
extern "C" void kernel_launch(void* const* d_in, const int* in_sizes, int n_in,
                              void* d_out, int out_size, void* d_ws, size_t ws_size,
                              hipStream_t stream)
{
    const float* X  = (const float*)d_in[0];   // q_input (B,T,C) fp32
    const float* Wq = (const float*)d_in[1];
    const float* Wk = (const float*)d_in[2];
    const float* Wv = (const float*)d_in[3];
    const int*   M  = (const int*)d_in[4];     // attn_mask (B,T) int32
    float* out = (float*)d_out;                // (B,T,HS) fp32

    __hip_bfloat16* Qp = (__hip_bfloat16*)d_ws;
    __hip_bfloat16* Kp = Qp + (size_t)NB * NT * NH;
    __hip_bfloat16* Vp = Kp + (size_t)NB * NT * NH;
    float* MVp = (float*)(Vp + (size_t)NB * NT * NH);
    __hip_bfloat16* Wtp = (__hip_bfloat16*)(MVp + NB * NH);
    float* Biasp = (float*)(Wtp + 192 * NC);

    prep_kernel<<<449, 256, 0, stream>>>(Wq, Wk, Wv, M, Wtp, Biasp, MVp);
    qkv_kernel<<<NB * NT / MT, 256, 0, stream>>>(X, Wtp, Qp, Kp, Vp, MVp);
    attn_kernel<<<512, 256, 0, stream>>>(Qp, Kp, Vp, Biasp, MVp, out);
}